// Round 2
// baseline (425.399 us; speedup 1.0000x reference)
//
#include <hip/hip_runtime.h>

// HaarDownSampling3D: x (2,32,64,128,128) f32 -> out (8,2,32,32,64,64) f32
// Separable Haar butterfly over each 2x2x2 block, /8, subband-major output.
// Memory-bound: 256 MiB in + 256 MiB out, zero reuse. One thread handles
// two adjacent 2x2x2 blocks along W (reads 4x float4, writes 8x float2).

namespace {
constexpr int Bc  = 64;            // B*C fused (2*32)
constexpr int Ld  = 64, Hd = 128, Wd = 128;
constexpr int L2  = Ld / 2, H2 = Hd / 2, W2 = Wd / 2;   // 32, 64, 64
constexpr int HW  = Hd * Wd;                             // 16384
constexpr size_t IN_BC   = (size_t)Ld * Hd * Wd;         // 1048576
constexpr size_t OUT_BC  = (size_t)L2 * H2 * W2;         // 131072
constexpr size_t OUT_SUB = (size_t)Bc * OUT_BC;          // 8388608
constexpr int WPAIRS = W2 / 2;                           // 32 thread-pairs per row
constexpr int NTHREADS = Bc * L2 * H2 * WPAIRS;          // 4194304
}

__global__ __launch_bounds__(256) void haar3d_kernel(
    const float* __restrict__ x, float* __restrict__ out) {
  int t = blockIdx.x * 256 + threadIdx.x;

  int wp = t & (WPAIRS - 1);      // which float4 along W (2 output cols)
  int r  = t >> 5;                // log2(WPAIRS) = 5
  int j  = r & (H2 - 1);          // output H index
  r >>= 6;                        // log2(H2) = 6
  int i  = r & (L2 - 1);          // output L index
  int bc = r >> 5;                // log2(L2) = 5

  const float* p = x + (size_t)bc * IN_BC + (size_t)(2 * i) * HW
                     + (size_t)(2 * j) * Wd + 4 * wp;
  float4 a0p0 = *(const float4*)(p);             // l=2i,   h=2j
  float4 a0p1 = *(const float4*)(p + Wd);        // l=2i,   h=2j+1
  float4 a1p0 = *(const float4*)(p + HW);        // l=2i+1, h=2j
  float4 a1p1 = *(const float4*)(p + HW + Wd);   // l=2i+1, h=2j+1

  float2 res[8];
#pragma unroll
  for (int e = 0; e < 2; ++e) {   // e = which 2x2x2 block within the float4
    float g[2][2][2];             // [a=L][p=H][q=W], static-indexed only
    g[0][0][0] = e ? a0p0.z : a0p0.x;  g[0][0][1] = e ? a0p0.w : a0p0.y;
    g[0][1][0] = e ? a0p1.z : a0p1.x;  g[0][1][1] = e ? a0p1.w : a0p1.y;
    g[1][0][0] = e ? a1p0.z : a1p0.x;  g[1][0][1] = e ? a1p0.w : a1p0.y;
    g[1][1][0] = e ? a1p1.z : a1p1.x;  g[1][1][1] = e ? a1p1.w : a1p1.y;

    // W butterfly: wv[a][p][z]  (z=0 low, z=1 high)
    float wv[2][2][2];
#pragma unroll
    for (int a = 0; a < 2; ++a)
#pragma unroll
      for (int pp = 0; pp < 2; ++pp) {
        wv[a][pp][0] = g[a][pp][0] + g[a][pp][1];
        wv[a][pp][1] = g[a][pp][0] - g[a][pp][1];
      }
    // H butterfly: m[a][y][z]
    float m[2][2][2];
#pragma unroll
    for (int a = 0; a < 2; ++a)
#pragma unroll
      for (int z = 0; z < 2; ++z) {
        m[a][0][z] = wv[a][0][z] + wv[a][1][z];
        m[a][1][z] = wv[a][0][z] - wv[a][1][z];
      }
    // L butterfly -> subband s = xsel*4 + y*2 + z, scaled by 1/8
#pragma unroll
    for (int y = 0; y < 2; ++y)
#pragma unroll
      for (int z = 0; z < 2; ++z) {
        float lo = (m[0][y][z] + m[1][y][z]) * 0.125f;
        float hi = (m[0][y][z] - m[1][y][z]) * 0.125f;
        int slo = 0 * 4 + y * 2 + z;
        int shi = 1 * 4 + y * 2 + z;
        if (e == 0) { res[slo].x = lo; res[shi].x = hi; }
        else        { res[slo].y = lo; res[shi].y = hi; }
      }
  }

  size_t obase = (size_t)bc * OUT_BC + (size_t)i * (H2 * W2)
               + (size_t)j * W2 + 2 * wp;
#pragma unroll
  for (int s = 0; s < 8; ++s) {
    *(float2*)(out + (size_t)s * OUT_SUB + obase) = res[s];
  }
}

extern "C" void kernel_launch(void* const* d_in, const int* in_sizes, int n_in,
                              void* d_out, int out_size, void* d_ws, size_t ws_size,
                              hipStream_t stream) {
  const float* x = (const float*)d_in[0];
  float* out = (float*)d_out;
  haar3d_kernel<<<NTHREADS / 256, 256, 0, stream>>>(x, out);
}